// Round 8
// baseline (1315.491 us; speedup 1.0000x reference)
//
#include <hip/hip_runtime.h>

// Hamiltonian GNN fwd+grad, out = state - DT*dH.
// Round 8: fused 2-layer MLP kernel (mlp2): layer1 -> h1 in 64KB swizzled LDS
// tile (vectorized epilogue for gathers/bias/relu/mask) -> layer2 with A from
// LDS. Replaces 22 edge GEMM dispatches with 11; kills h1 HBM round-trips.

#define E_ROWS 16384
#define N_ROWS 4096
#define ALL_ROWS 20480
#define DT_F   0.01f

typedef unsigned char u8;
typedef unsigned short u16;
typedef unsigned long long u64;
typedef __attribute__((ext_vector_type(8))) short short8v;
typedef __attribute__((ext_vector_type(4))) float f32x4;

__device__ __forceinline__ u16 f2b(float f) {
    union { float f; unsigned u; } v; v.f = f;
    unsigned r = v.u + 0x7FFF + ((v.u >> 16) & 1);
    return (u16)(r >> 16);
}
__device__ __forceinline__ float b2f(u16 u) {
    union { unsigned u; float f; } v; v.u = ((unsigned)u) << 16;
    return v.f;
}
__device__ __forceinline__ void gld16(const u16* g, u16* l) {
    __builtin_amdgcn_global_load_lds((const __attribute__((address_space(1))) void*)g,
                                     (__attribute__((address_space(3))) void*)l, 16, 0, 0);
}

// ---------------------------------------------------------------------------
// Fused 2-layer MLP over 64 rows x 512 cols. 512 threads = 8 waves (2x4).
// MODE 0 (fwd edge):  h1 = relu(A@B1^T + G12[s|r] + b1) [mask->maskio];
//                     Cout = h1@B2^T + Cout + b2
// MODE 1 (bwd edge):  dh1 = (A@B1^T) * maskio; dh1 -> h1hbm;
//                     Cout = dh1@B2^T + Cout
// MODE 2 (decoder):   dh1 = (A@B1^T + b1 > 0) ? w2vec : 0;
//                     Cout = dh1@B2^T                (fresh write)
// LDS: Hs 64KB h1 tile (XOR-swizzled rows; bytes 0..8191 double as phase-1 A
// staging before the dump), Bs 2x32KB W-chunk double buffer. Total 128KB.
// ---------------------------------------------------------------------------
template<int MODE>
__global__ __launch_bounds__(512)
void mlp2(const u16* __restrict__ A, const u16* __restrict__ B1t,
          const u16* __restrict__ B2t,
          const float* __restrict__ bias1, const float* __restrict__ bias2,
          const u16* __restrict__ G12b,
          const int* __restrict__ sidx, const int* __restrict__ ridx,
          u8* __restrict__ maskio, u16* __restrict__ h1hbm,
          u16* __restrict__ Cout, const float* __restrict__ w2vec)
{
    __shared__ u16 Hs[64 * 512];      // 64KB
    __shared__ u16 Bs[2][32 * 512];   // 64KB
    char* HsB = (char*)Hs;

    const int tid = threadIdx.x;
    const int lane = tid & 63;
    const int wv = tid >> 6;          // 0..7
    const int wr = wv >> 2;           // 0..1 (32-row half)
    const int wc = wv & 3;            // 0..3 (128-col quarter)

    int id = blockIdx.x;
    id = (id & 7) * (gridDim.x >> 3) + (id >> 3);   // XCD chunking (grid%8==0)
    const int rowBase = id * 64;

    const int srow = lane & 15;
    const int slotk = (lane >> 4) << 3;
    const int fro = ((lane >> 4) << 7) + ((lane & 15) << 3);

    f32x4 acc[2][8];
#pragma unroll
    for (int i = 0; i < 2; ++i)
#pragma unroll
        for (int j = 0; j < 8; ++j)
            acc[i][j] = (f32x4){0.f, 0.f, 0.f, 0.f};

    // ---------------- phase 1: acc = A @ B1^T ----------------
    // staging: 36 chunks (4 A into Hs[buf*2048], 32 B into Bs[buf])
    auto stage1 = [&](int buf, int kb) {
#pragma unroll
        for (int q = 0; q < 5; ++q) {
            const int c = wv + (q << 3);
            if (c >= 36) continue;
            if (c < 4)
                gld16(A + (size_t)(rowBase + c * 16 + srow) * 512 + kb + slotk,
                      Hs + buf * 2048 + c * 512);
            else
                gld16(B1t + (size_t)((c - 4) * 16 + srow) * 512 + kb + slotk,
                      &Bs[buf][(c - 4) * 512]);
        }
    };
    stage1(0, 0);
    asm volatile("s_waitcnt vmcnt(0)" ::: "memory");
    __builtin_amdgcn_s_barrier();
    asm volatile("" ::: "memory");
#pragma unroll
    for (int t = 0; t < 16; ++t) {
        const int cur = t & 1;
        if (t < 15) stage1(cur ^ 1, (t + 1) * 32);
        const u16* AsC = Hs + cur * 2048;
        short8v af[2], bf[8];
#pragma unroll
        for (int i = 0; i < 2; ++i)
            af[i] = *(const short8v*)&AsC[((wr << 1) + i) * 512 + fro];
#pragma unroll
        for (int j = 0; j < 8; ++j)
            bf[j] = *(const short8v*)&Bs[cur][((wc << 3) + j) * 512 + fro];
#pragma unroll
        for (int i = 0; i < 2; ++i)
#pragma unroll
            for (int j = 0; j < 8; ++j)
                acc[i][j] = __builtin_amdgcn_mfma_f32_16x16x32_bf16(af[i], bf[j], acc[i][j], 0, 0, 0);
        if (t < 15) {
            asm volatile("s_waitcnt vmcnt(0)" ::: "memory");
            __builtin_amdgcn_s_barrier();
            asm volatile("" ::: "memory");
        }
    }
    __syncthreads();

    // dump raw acc -> Hs (swizzled)
#pragma unroll
    for (int i = 0; i < 2; ++i)
#pragma unroll
        for (int r = 0; r < 4; ++r) {
            const int drow = wr * 32 + i * 16 + ((lane >> 4) << 2) + r;
#pragma unroll
            for (int j = 0; j < 8; ++j) {
                const int dcol = wc * 128 + j * 16 + (lane & 15);
                int db = drow * 1024 + dcol * 2;
                db ^= (drow & 7) << 4;
                *(u16*)(HsB + db) = f2b(acc[i][j][r]);
            }
        }
    __syncthreads();

    // epilogue 1 (vectorized): finish h1, write back to Hs (+ HBM side effects)
    {
        const int rloc = tid >> 6;            // 0..7
        const int seg = tid & 63;
        const int col0 = seg << 3;
#pragma unroll
        for (int p = 0; p < 8; ++p) {
            const int row = p * 8 + rloc;
            const int grow = rowBase + row;
            int byte = row * 1024 + col0 * 2;
            byte ^= (row & 7) << 4;
            const short8v sv = *(const short8v*)(HsB + byte);
            float v[8];
#pragma unroll
            for (int e = 0; e < 8; ++e) v[e] = b2f((u16)sv[e]);

            if (MODE == 0) {
                const int si = sidx[grow], ri = ridx[grow];
                const short8v g1 = *(const short8v*)&G12b[(size_t)si * 1024 + col0];
                const short8v g2 = *(const short8v*)&G12b[(size_t)ri * 1024 + 512 + col0];
                const float4 b0 = *(const float4*)&bias1[col0];
                const float4 b1v = *(const float4*)&bias1[col0 + 4];
                const float bl[8] = {b0.x, b0.y, b0.z, b0.w, b1v.x, b1v.y, b1v.z, b1v.w};
#pragma unroll
                for (int e = 0; e < 8; ++e) v[e] += b2f((u16)g1[e]) + b2f((u16)g2[e]) + bl[e];
                u64 mm = 0;
#pragma unroll
                for (int e = 0; e < 8; ++e) {
                    const bool m = v[e] > 0.f;
                    mm |= (u64)(m ? 1 : 0) << (e * 8);
                    if (!m) v[e] = 0.f;
                }
                *(u64*)&maskio[(size_t)grow * 512 + col0] = mm;
                short8v h;
#pragma unroll
                for (int e = 0; e < 8; ++e) h[e] = (short)f2b(v[e]);
                *(short8v*)(HsB + byte) = h;
            } else if (MODE == 1) {
                const u64 mm = *(const u64*)&maskio[(size_t)grow * 512 + col0];
                short8v h;
#pragma unroll
                for (int e = 0; e < 8; ++e) {
                    if (!((mm >> (e * 8)) & 0xff)) v[e] = 0.f;
                    h[e] = (short)f2b(v[e]);
                }
                *(short8v*)&h1hbm[(size_t)grow * 512 + col0] = h;
                *(short8v*)(HsB + byte) = h;
            } else {
                const float4 b0 = *(const float4*)&bias1[col0];
                const float4 b1v = *(const float4*)&bias1[col0 + 4];
                const float4 w0 = *(const float4*)&w2vec[col0];
                const float4 w1 = *(const float4*)&w2vec[col0 + 4];
                const float bl[8] = {b0.x, b0.y, b0.z, b0.w, b1v.x, b1v.y, b1v.z, b1v.w};
                const float wl[8] = {w0.x, w0.y, w0.z, w0.w, w1.x, w1.y, w1.z, w1.w};
                short8v h;
#pragma unroll
                for (int e = 0; e < 8; ++e)
                    h[e] = (v[e] + bl[e] > 0.f) ? (short)f2b(wl[e]) : (short)0;
                *(short8v*)(HsB + byte) = h;
            }
        }
    }
    __syncthreads();

    // ---------------- phase 2: acc = h1(LDS) @ B2^T ----------------
#pragma unroll
    for (int i = 0; i < 2; ++i)
#pragma unroll
        for (int j = 0; j < 8; ++j)
            acc[i][j] = (f32x4){0.f, 0.f, 0.f, 0.f};

    auto stage2 = [&](int buf, int kb) {
#pragma unroll
        for (int q = 0; q < 4; ++q) {
            const int c = wv + (q << 3);
            gld16(B2t + (size_t)(c * 16 + srow) * 512 + kb + slotk, &Bs[buf][c * 512]);
        }
    };
    stage2(0, 0);
    __syncthreads();   // waits vmcnt+lgkm: staging done AND epilogue-1 LDS writes drained
#pragma unroll
    for (int t = 0; t < 16; ++t) {
        const int cur = t & 1;
        if (t < 15) stage2(cur ^ 1, (t + 1) * 32);
        short8v af[2], bf[8];
#pragma unroll
        for (int i = 0; i < 2; ++i) {
            const int arow = wr * 32 + i * 16 + (lane & 15);
            int ab = arow * 1024 + t * 64 + ((lane >> 4) << 4);
            ab ^= (arow & 7) << 4;
            af[i] = *(const short8v*)(HsB + ab);
        }
#pragma unroll
        for (int j = 0; j < 8; ++j)
            bf[j] = *(const short8v*)&Bs[cur][((wc << 3) + j) * 512 + fro];
#pragma unroll
        for (int i = 0; i < 2; ++i)
#pragma unroll
            for (int j = 0; j < 8; ++j)
                acc[i][j] = __builtin_amdgcn_mfma_f32_16x16x32_bf16(af[i], bf[j], acc[i][j], 0, 0, 0);
        if (t < 15) {
            asm volatile("s_waitcnt vmcnt(0)" ::: "memory");
            __builtin_amdgcn_s_barrier();
            asm volatile("" ::: "memory");
        }
    }
    __syncthreads();

    // dump acc2 -> Hs (h1 no longer needed)
#pragma unroll
    for (int i = 0; i < 2; ++i)
#pragma unroll
        for (int r = 0; r < 4; ++r) {
            const int drow = wr * 32 + i * 16 + ((lane >> 4) << 2) + r;
#pragma unroll
            for (int j = 0; j < 8; ++j) {
                const int dcol = wc * 128 + j * 16 + (lane & 15);
                int db = drow * 1024 + dcol * 2;
                db ^= (drow & 7) << 4;
                *(u16*)(HsB + db) = f2b(acc[i][j][r]);
            }
        }
    __syncthreads();

    // epilogue 2 (vectorized): Cout = raw (+Cin) (+b2)
    {
        const int rloc = tid >> 6;
        const int seg = tid & 63;
        const int col0 = seg << 3;
#pragma unroll
        for (int p = 0; p < 8; ++p) {
            const int row = p * 8 + rloc;
            const int grow = rowBase + row;
            int byte = row * 1024 + col0 * 2;
            byte ^= (row & 7) << 4;
            const short8v sv = *(const short8v*)(HsB + byte);
            float v[8];
#pragma unroll
            for (int e = 0; e < 8; ++e) v[e] = b2f((u16)sv[e]);
            if (MODE == 0 || MODE == 1) {
                const short8v c8 = *(const short8v*)&Cout[(size_t)grow * 512 + col0];
#pragma unroll
                for (int e = 0; e < 8; ++e) v[e] += b2f((u16)c8[e]);
            }
            if (MODE == 0) {
                const float4 b0 = *(const float4*)&bias2[col0];
                const float4 b1v = *(const float4*)&bias2[col0 + 4];
                const float bl[8] = {b0.x, b0.y, b0.z, b0.w, b1v.x, b1v.y, b1v.z, b1v.w};
#pragma unroll
                for (int e = 0; e < 8; ++e) v[e] += bl[e];
            }
            short8v res;
#pragma unroll
            for (int e = 0; e < 8; ++e) res[e] = (short)f2b(v[e]);
            *(short8v*)&Cout[(size_t)grow * 512 + col0] = res;
        }
    }
}

// ---------------------------------------------------------------------------
// bf16 MFMA GEMM (r7 structure): tile BM x (WN*64), 4 waves, LDS-routed
// vectorized epilogue.
// ---------------------------------------------------------------------------
template<int BM, int WM, int WN, int KTOT, int LDA, int LDC,
         bool ADD_C, bool GATHER2, bool BIAS, bool RELU_MASK, bool APPLY_MASK,
         bool WF32, bool WBF16, bool DUALOUT, bool ROWDOT, bool BSEL>
__global__ __launch_bounds__(256)
void bgemm(const u16* __restrict__ A, const u16* __restrict__ Bt, const u16* __restrict__ Bt2,
           float* __restrict__ C, u16* __restrict__ Cb,
           const u16* __restrict__ Cinb, const float* __restrict__ bias,
           const float* __restrict__ bias2, const u16* __restrict__ G12b,
           const int* __restrict__ sidx, const int* __restrict__ ridx,
           u8* __restrict__ maskw, u16* __restrict__ C2b,
           const float* __restrict__ wvec, const float* __restrict__ wvec2,
           float* __restrict__ outp)
{
    constexpr int BN = WN * 64;
    constexpr int NA = BM / 16;
    constexpr int TC = (BM + BN) / 16;
    constexpr int PER = TC / 4;
    constexpr int IFRAG = BM / WM / 16;
    __shared__ u16 Ls[BM * BN];

    const int tid = threadIdx.x;
    const int lane = tid & 63;
    const int wv = tid >> 6;
    const int wr = wv / WN;
    const int wc = wv % WN;

    const int gx = gridDim.x;
    int id = blockIdx.y * gx + blockIdx.x;
    const int nwg = gx * gridDim.y;
    id = (id & 7) * (nwg >> 3) + (id >> 3);
    const int bx = id % gx;
    const int by = id / gx;
    const int rowBase = by * BM;
    const int colBase = bx * BN;

    const u16* BtU = Bt;
    const float* biasU = bias;
    const float* wvecU = wvec;
    if (BSEL && rowBase >= E_ROWS) { BtU = Bt2; biasU = bias2; wvecU = wvec2; }

    const int srow = lane & 15;
    const int slotk = (lane >> 4) << 3;

    const u16* srcs[PER];
    int dstoff[PER];
#pragma unroll
    for (int q = 0; q < PER; ++q) {
        const int c = wv + (q << 2);
        if (c < NA)
            srcs[q] = A + (size_t)(rowBase + c * 16 + srow) * LDA + slotk;
        else
            srcs[q] = BtU + (size_t)(colBase + (c - NA) * 16 + srow) * KTOT + slotk;
        dstoff[q] = c * 512;
    }

    f32x4 acc[IFRAG][4];
#pragma unroll
    for (int i = 0; i < IFRAG; ++i)
#pragma unroll
        for (int j = 0; j < 4; ++j)
            acc[i][j] = (f32x4){0.f, 0.f, 0.f, 0.f};

    const int fro = ((lane >> 4) << 7) + ((lane & 15) << 3);

    for (int kb = 0; kb < KTOT; kb += 32) {
#pragma unroll
        for (int q = 0; q < PER; ++q)
            gld16(srcs[q] + kb, &Ls[dstoff[q]]);
        __syncthreads();
        short8v af[IFRAG], bfm[4];
#pragma unroll
        for (int i = 0; i < IFRAG; ++i)
            af[i] = *(const short8v*)&Ls[((wr * IFRAG + i) << 9) + fro];
#pragma unroll
        for (int j = 0; j < 4; ++j)
            bfm[j] = *(const short8v*)&Ls[((NA + (wc << 2) + j) << 9) + fro];
#pragma unroll
        for (int i = 0; i < IFRAG; ++i)
#pragma unroll
            for (int j = 0; j < 4; ++j)
                acc[i][j] = __builtin_amdgcn_mfma_f32_16x16x32_bf16(af[i], bfm[j], acc[i][j], 0, 0, 0);
        __syncthreads();
    }

    if constexpr (WF32) {
        const int colB = colBase + wc * 64 + (lane & 15);
        const int rowB = rowBase + wr * (BM / WM) + ((lane >> 4) << 2);
        float bcol[4];
#pragma unroll
        for (int j = 0; j < 4; ++j) bcol[j] = biasU[colB + (j << 4)];
#pragma unroll
        for (int i = 0; i < IFRAG; ++i)
#pragma unroll
            for (int r = 0; r < 4; ++r) {
                const int row = rowB + (i << 4) + r;
#pragma unroll
                for (int j = 0; j < 4; ++j)
                    C[(size_t)row * LDC + colB + (j << 4)] = acc[i][j][r] + bcol[j];
            }
    } else {
        const int colL = wc * 64 + (lane & 15);
        const int rowL0 = wr * (BM / WM) + ((lane >> 4) << 2);
#pragma unroll
        for (int i = 0; i < IFRAG; ++i)
#pragma unroll
            for (int r = 0; r < 4; ++r) {
                const int row = rowL0 + (i << 4) + r;
#pragma unroll
                for (int j = 0; j < 4; ++j) {
                    const int col = colL + (j << 4);
                    int byte = row * (BN * 2) + col * 2;
                    byte ^= (row & 7) << 4;
                    *(u16*)((char*)Ls + byte) = f2b(acc[i][j][r]);
                }
            }
        __syncthreads();

        constexpr int TPR = BN / 8;
        constexpr int RPP = 256 / TPR;
        constexpr int NP = BM / RPP;
        const int rloc = tid / TPR;
        const int seg = tid % TPR;
        const int col0 = seg * 8;
        const bool upper = DUALOUT && (colBase >= 512);
#pragma unroll
        for (int p = 0; p < NP; ++p) {
            const int row = p * RPP + rloc;
            const int grow = rowBase + row;
            const int gcol = colBase + col0;
            int byte = row * (BN * 2) + col0 * 2;
            byte ^= (row & 7) << 4;
            const short8v sv = *(const short8v*)((const char*)Ls + byte);
            float v[8];
#pragma unroll
            for (int e = 0; e < 8; ++e) v[e] = b2f((u16)sv[e]);

            if (DUALOUT && upper) {
                short8v res;
#pragma unroll
                for (int e = 0; e < 8; ++e) res[e] = (short)f2b(v[e]);
                *(short8v*)&C2b[(size_t)grow * 512 + (gcol - 512)] = res;
                continue;
            }
            if (GATHER2) {
                const int si = sidx[grow], ri = ridx[grow];
                const short8v g1 = *(const short8v*)&G12b[(size_t)si * 1024 + gcol];
                const short8v g2 = *(const short8v*)&G12b[(size_t)ri * 1024 + 512 + gcol];
#pragma unroll
                for (int e = 0; e < 8; ++e) v[e] += b2f((u16)g1[e]) + b2f((u16)g2[e]);
            }
            if (ADD_C) {
                const short8v c8 = *(const short8v*)&Cinb[(size_t)grow * LDC + gcol];
#pragma unroll
                for (int e = 0; e < 8; ++e) v[e] += b2f((u16)c8[e]);
            }
            if (BIAS) {
                const float4 b0 = *(const float4*)&biasU[gcol];
                const float4 b1 = *(const float4*)&biasU[gcol + 4];
                v[0] += b0.x; v[1] += b0.y; v[2] += b0.z; v[3] += b0.w;
                v[4] += b1.x; v[5] += b1.y; v[6] += b1.z; v[7] += b1.w;
            }
            if (RELU_MASK) {
                u64 mm = 0;
#pragma unroll
                for (int e = 0; e < 8; ++e) {
                    const bool m = v[e] > 0.f;
                    mm |= (u64)(m ? 1 : 0) << (e * 8);
                    if (!m) v[e] = 0.f;
                }
                *(u64*)&maskw[(size_t)grow * 512 + gcol] = mm;
            }
            if (APPLY_MASK) {
                const u64 mm = *(const u64*)&maskw[(size_t)grow * 512 + gcol];
#pragma unroll
                for (int e = 0; e < 8; ++e)
                    if (!((mm >> (e * 8)) & 0xff)) v[e] = 0.f;
            }
            if (ROWDOT) {
                const float4 w0 = *(const float4*)&wvecU[gcol];
                const float4 w1 = *(const float4*)&wvecU[gcol + 4];
                float rds = v[0] * w0.x + v[1] * w0.y + v[2] * w0.z + v[3] * w0.w
                          + v[4] * w1.x + v[5] * w1.y + v[6] * w1.z + v[7] * w1.w;
#pragma unroll
                for (int m = 1; m < TPR; m <<= 1) rds += __shfl_xor(rds, m);
                if (seg == 0) atomicAdd(outp + grow, -DT_F * rds);
            }
            if (WBF16) {
                short8v res;
#pragma unroll
                for (int e = 0; e < 8; ++e) res[e] = (short)f2b(v[e]);
                *(short8v*)&Cb[(size_t)grow * LDC + gcol] = res;
            }
        }
    }
}

// ---------------------------------------------------------------------------
struct WArgs {
    const float* src[10];
    u16* dstP[10];
    u16* dstT[10];
    int ldP[10], ldT[10];
};

__global__ void wcvt_kernel(WArgs a)
{
    const int i = blockIdx.z;
    const float* W = a.src[i];
    u16* P = a.dstP[i]; const int lp = a.ldP[i];
    u16* T = a.dstT[i]; const int lt = a.ldT[i];
    __shared__ u16 t[64][66];
    const int rb = blockIdx.y << 6, cb = blockIdx.x << 6;
    const int tr = threadIdx.x >> 4;
    const int tc = (threadIdx.x & 15) << 2;
#pragma unroll
    for (int rr = 0; rr < 4; ++rr) {
        const int r = tr + (rr << 4);
        const float4 v = *(const float4*)&W[(size_t)(rb + r) * 512 + cb + tc];
        ushort4 u; u.x = f2b(v.x); u.y = f2b(v.y); u.z = f2b(v.z); u.w = f2b(v.w);
        *(ushort4*)&P[(size_t)(rb + r) * lp + cb + tc] = u;
        t[r][tc] = u.x; t[r][tc + 1] = u.y; t[r][tc + 2] = u.z; t[r][tc + 3] = u.w;
    }
    __syncthreads();
#pragma unroll
    for (int rr = 0; rr < 4; ++rr) {
        const int n = tr + (rr << 4);
        ushort4 u;
        u.x = t[tc][n]; u.y = t[tc + 1][n]; u.z = t[tc + 2][n]; u.w = t[tc + 3][n];
        *(ushort4*)&T[(size_t)(cb + n) * lt + rb + tc] = u;
    }
}

// ---------------------------------------------------------------------------
__device__ void csr_build(const int* __restrict__ idx, int* __restrict__ starts,
                          int* __restrict__ eids)
{
    __shared__ int hist[4096];
    __shared__ int scanbuf[1024];
    const int t = threadIdx.x;
    for (int i = t; i < 4096; i += 1024) hist[i] = 0;
    __syncthreads();
    for (int e = t; e < 16384; e += 1024) atomicAdd(&hist[idx[e]], 1);
    __syncthreads();
    const int base = t << 2;
    const int l0 = hist[base], l1 = hist[base + 1], l2 = hist[base + 2], l3 = hist[base + 3];
    const int lsum = l0 + l1 + l2 + l3;
    scanbuf[t] = lsum;
    __syncthreads();
    for (int ofs = 1; ofs < 1024; ofs <<= 1) {
        const int v = scanbuf[t];
        const int u = (t >= ofs) ? scanbuf[t - ofs] : 0;
        __syncthreads();
        scanbuf[t] = v + u;
        __syncthreads();
    }
    const int excl = scanbuf[t] - lsum;
    const int p0 = excl, p1 = p0 + l0, p2 = p1 + l1, p3 = p2 + l2;
    starts[base] = p0; starts[base + 1] = p1; starts[base + 2] = p2; starts[base + 3] = p3;
    if (t == 0) starts[4096] = 16384;
    __syncthreads();
    hist[base] = p0; hist[base + 1] = p1; hist[base + 2] = p2; hist[base + 3] = p3;
    __syncthreads();
    for (int e = t; e < 16384; e += 1024) {
        const int pos = atomicAdd(&hist[idx[e]], 1);
        eids[pos] = e;
    }
    __syncthreads();
    for (int n = t; n < 4096; n += 1024) {
        const int s0 = starts[n], s1 = hist[n];
        for (int i = s0 + 1; i < s1; ++i) {
            const int v = eids[i];
            int j = i - 1;
            while (j >= s0 && eids[j] > v) { eids[j + 1] = eids[j]; --j; }
            eids[j + 1] = v;
        }
    }
}

__global__ __launch_bounds__(1024) void csr2_kernel(const int* __restrict__ senders,
                                                    const int* __restrict__ receivers,
                                                    int* __restrict__ sst, int* __restrict__ seid,
                                                    int* __restrict__ rst, int* __restrict__ reid)
{
    if (blockIdx.x == 0) csr_build(receivers, rst, reid);
    else                 csr_build(senders, sst, seid);
}

__global__ void init_out_kernel(const float* __restrict__ state, float* __restrict__ out)
{
    const int t = blockIdx.x * 256 + threadIdx.x;
    out[t] = state[t];
}

__global__ void seg_agg_fwd_kernel(const u16* __restrict__ ehb, const int* __restrict__ starts,
                                   const int* __restrict__ eids, const u16* __restrict__ nhb,
                                   u16* __restrict__ nagg)
{
    const int n = blockIdx.x, c = threadIdx.x;
    const int s0 = starts[n], s1 = starts[n + 1];
    float a0 = 0.f, a1 = 0.f;
    for (int i = s0; i < s1; ++i) {
        const u16* p = ehb + (size_t)eids[i] * 512;
        a0 += b2f(p[c]); a1 += b2f(p[c + 256]);
    }
    u16* d = nagg + (size_t)n * 1024;
    const u16* s = nhb + (size_t)n * 512;
    d[c] = s[c]; d[c + 256] = s[c + 256];
    d[512 + c] = f2b(a0); d[768 + c] = f2b(a1);
}

__global__ void seg_sr_bwd_kernel(const u16* __restrict__ dh1e,
                                  const int* __restrict__ sst, const int* __restrict__ seid,
                                  const int* __restrict__ rst, const int* __restrict__ reid,
                                  u16* __restrict__ SR)
{
    const int n = blockIdx.x, c = threadIdx.x;
    float a0 = 0.f, a1 = 0.f, b0 = 0.f, b1 = 0.f;
    for (int i = sst[n]; i < sst[n + 1]; ++i) {
        const u16* p = dh1e + (size_t)seid[i] * 512;
        a0 += b2f(p[c]); a1 += b2f(p[c + 256]);
    }
    for (int i = rst[n]; i < rst[n + 1]; ++i) {
        const u16* p = dh1e + (size_t)reid[i] * 512;
        b0 += b2f(p[c]); b1 += b2f(p[c + 256]);
    }
    u16* d = SR + (size_t)n * 1024;
    d[c] = f2b(a0); d[c + 256] = f2b(a1);
    d[512 + c] = f2b(b0); d[768 + c] = f2b(b1);
}

__global__ void enc_h1_kernel(const float* __restrict__ x,
                              const float* __restrict__ W1e, const float* __restrict__ b1e,
                              const float* __restrict__ W1n, const float* __restrict__ b1n,
                              u16* __restrict__ h1b, u8* __restrict__ mask)
{
    const int idx = blockIdx.x * 256 + threadIdx.x;
    const int row = idx >> 7;
    const int c = (idx & 127) << 2;
    const bool edge = row < E_ROWS;
    const float* W1 = edge ? W1e : W1n;
    const float* b1 = edge ? b1e : b1n;
    const float xv = x[row];
    const float4 w = *(const float4*)&W1[c];
    const float4 b = *(const float4*)&b1[c];
    float4 v;
    v.x = fmaf(xv, w.x, b.x); v.y = fmaf(xv, w.y, b.y);
    v.z = fmaf(xv, w.z, b.z); v.w = fmaf(xv, w.w, b.w);
    uchar4 m;
    m.x = v.x > 0.f; m.y = v.y > 0.f; m.z = v.z > 0.f; m.w = v.w > 0.f;
    v.x = m.x ? v.x : 0.f; v.y = m.y ? v.y : 0.f;
    v.z = m.z ? v.z : 0.f; v.w = m.w ? v.w : 0.f;
    const size_t o = (size_t)row * 512 + c;
    ushort4 u; u.x = f2b(v.x); u.y = f2b(v.y); u.z = f2b(v.z); u.w = f2b(v.w);
    *(ushort4*)&h1b[o] = u;
    *(uchar4*)&mask[o] = m;
}

__global__ void ln_fwd_kernel(const float* __restrict__ x, u16* __restrict__ xhat_b,
                              u16* __restrict__ xb, float* __restrict__ rstd_save)
{
    const int row = blockIdx.x, tid = threadIdx.x;
    const float* p = x + (size_t)row * 512;
    const float a = p[tid], b = p[tid + 256];
    __shared__ float s1[256], s2[256];
    s1[tid] = a + b; s2[tid] = a * a + b * b;
    __syncthreads();
    for (int d = 128; d > 0; d >>= 1) {
        if (tid < d) { s1[tid] += s1[tid + d]; s2[tid] += s2[tid + d]; }
        __syncthreads();
    }
    const float mean = s1[0] * (1.f / 512.f);
    const float var = s2[0] * (1.f / 512.f) - mean * mean;
    const float r = rsqrtf(var + 1e-6f);
    const float ya = (a - mean) * r, yb = (b - mean) * r;
    const size_t o = (size_t)row * 512 + tid;
    xhat_b[o] = f2b(ya); xhat_b[o + 256] = f2b(yb);
    xb[o] = f2b(ya); xb[o + 256] = f2b(yb);
    if (tid == 0) rstd_save[row] = r;
}

__global__ void ln_bwd_kernel(u16* __restrict__ d, const u16* __restrict__ xhat_b,
                              const float* __restrict__ rstd)
{
    const int row = blockIdx.x, tid = threadIdx.x;
    u16* p = d + (size_t)row * 512;
    const u16* xh = xhat_b + (size_t)row * 512;
    const float da = b2f(p[tid]), dbv = b2f(p[tid + 256]);
    const float xa = b2f(xh[tid]), xbv = b2f(xh[tid + 256]);
    __shared__ float s1[256], s2[256];
    s1[tid] = da + dbv; s2[tid] = da * xa + dbv * xbv;
    __syncthreads();
    for (int dd = 128; dd > 0; dd >>= 1) {
        if (tid < dd) { s1[tid] += s1[tid + dd]; s2[tid] += s2[tid + dd]; }
        __syncthreads();
    }
    const float m1 = s1[0] * (1.f / 512.f);
    const float m2 = s2[0] * (1.f / 512.f);
    const float r = rstd[row];
    p[tid] = f2b(r * (da - m1 - xa * m2));
    p[tid + 256] = f2b(r * (dbv - m1 - xbv * m2));
}

__global__ void gather_add_kernel(u16* __restrict__ dst, const u16* __restrict__ src,
                                  const int* __restrict__ idx)
{
    const int t = blockIdx.x * 256 + threadIdx.x;
    const int row = t >> 6;
    const int c = (t & 63) << 3;
    const size_t o = (size_t)row * 512 + c;
    short8v a = *(const short8v*)&dst[o];
    const short8v g = *(const short8v*)&src[(size_t)idx[row] * 512 + c];
    short8v r;
#pragma unroll
    for (int i = 0; i < 8; ++i)
        r[i] = (short)f2b(b2f((u16)a[i]) + b2f((u16)g[i]));
    *(short8v*)&dst[o] = r;
}

// ---------------------------------------------------------------------------
extern "C" void kernel_launch(void* const* d_in, const int* in_sizes, int n_in,
                              void* d_out, int out_size, void* d_ws, size_t ws_size,
                              hipStream_t stream)
{
    (void)in_sizes; (void)n_in; (void)out_size; (void)ws_size;
    const float* state     = (const float*)d_in[0];
    const int*   senders   = (const int*)d_in[1];
    const int*   receivers = (const int*)d_in[2];
    const float* enc_e_W1 = (const float*)d_in[3];
    const float* enc_e_b1 = (const float*)d_in[4];
    const float* enc_e_W2 = (const float*)d_in[5];
    const float* enc_e_b2 = (const float*)d_in[6];
    const float* enc_n_W1 = (const float*)d_in[7];
    const float* enc_n_b1 = (const float*)d_in[8];
    const float* enc_n_W2 = (const float*)d_in[9];
    const float* enc_n_b2 = (const float*)d_in[10];
    const float* pe_W1 = (const float*)d_in[11];
    const float* pe_b1 = (const float*)d_in[12];
    const float* pe_W2 = (const float*)d_in[13];
    const float* pe_b2 = (const float*)d_in[14];
    const float* pn_W1 = (const float*)d_in[15];
    const float* pn_b1 = (const float*)d_in[16];
    const float* pn_W2 = (const float*)d_in[17];
    const float* pn_b2 = (const float*)d_in[18];
    const float* de_W1 = (const float*)d_in[19];
    const float* de_b1 = (const float*)d_in[20];
    const float* de_W2 = (const float*)d_in[21];
    float* out = (float*)d_out;

    const size_t EL = (size_t)E_ROWS * 512, NL = (size_t)N_ROWS * 512;
    const size_t AL = (size_t)ALL_ROWS * 512;
    const size_t LL = 512 * 512;
    char* w = (char*)d_ws;
    size_t off = 0;
    auto carve = [&](size_t bytes) -> char* {
        char* p = w + off;
        off += (bytes + 255) & ~(size_t)255;
        return p;
    };
    u16* wb = (u16*)carve(20 * LL * 2);
    u16* WT0 = wb;           u16* WT1 = wb + LL;      u16* WT2 = wb + 2 * LL;
    u16* WT34 = wb + 3 * LL;                          u16* WT5 = wb + 5 * LL;
    u16* WT8 = wb + 6 * LL;  u16* WT9 = wb + 7 * LL;
    u16* WP0 = wb + 8 * LL;  u16* WP1 = wb + 9 * LL;  u16* WP2 = wb + 10 * LL;
    u16* WP5 = wb + 11 * LL; u16* WP8 = wb + 12 * LL; u16* WP9 = wb + 13 * LL;
    u16* WT67 = wb + 14 * LL;   // [512][1024]
    u16* WP34c = wb + 16 * LL;  // [512][1024]
    u16* WP67 = wb + 18 * LL;   // [1024][512]

    float* eh  = (float*)carve(AL * 4);
    u16* ehb   = (u16*)carve(EL * 2);
    u16* nhb   = (u16*)carve(NL * 2);
    u16* h1eb  = (u16*)carve(EL * 2);
    u16* h1nb  = (u16*)carve(NL * 2);
    u16* eh0b  = (u16*)carve(EL * 2);
    u16* nh0b  = (u16*)carve(NL * 2);
    u8* menc   = (u8*)carve(AL);
    u16* G1b   = (u16*)carve(NL * 2);
    u16* G12b  = (u16*)carve(NL * 2 * 2);
    u16* nsr   = (u16*)carve(NL * 2 * 2);
    float* rstd = (float*)carve(ALL_ROWS * 4);
    u8* mpe    = (u8*)carve(5 * EL);
    u8* mpn    = (u8*)carve(5 * NL);
    int* rst  = (int*)carve(4097 * 4);
    int* reid = (int*)carve(16384 * 4);
    int* sst  = (int*)carve(4097 * 4);
    int* seid = (int*)carve(16384 * 4);

    const dim3 blk(256);
    const dim3 blk512(512);
    const dim3 gF(E_ROWS / 64);               // fused mlp2: 256 blocks
    const dim3 gA(4, ALL_ROWS / 128);         // merged enc/final: 640 blocks
    const dim3 gN512(8, N_ROWS / 64);
    const dim3 gN1024(16, N_ROWS / 64);
    const float* fp = nullptr;
    u16* up = nullptr;
    const u16* cup = nullptr;
    const int* ip = nullptr;
    u8* mp = nullptr;
    float* f2p = nullptr;

    WArgs wa;
    const float* wsrc[10] = { enc_e_W2, enc_n_W2, pe_W1, pe_W1 + LL, pe_W1 + 2 * LL,
                              pe_W2, pn_W1, pn_W1 + LL, pn_W2, de_W1 };
    u16* dstP[10] = { WP0, WP1, WP2, WP34c, WP34c + 512, WP5, WP67, WP67 + LL, WP8, WP9 };
    int  ldP [10] = { 512, 512, 512, 1024,  1024,        512, 512,  512,       512, 512 };
    u16* dstT[10] = { WT0, WT1, WT2, WT34, WT34 + LL, WT5, WT67, WT67 + 512, WT8, WT9 };
    int  ldT [10] = { 512, 512, 512, 512,  512,       512, 1024, 1024,       512, 512 };
    for (int i = 0; i < 10; ++i) {
        wa.src[i] = wsrc[i]; wa.dstP[i] = dstP[i]; wa.dstT[i] = dstT[i];
        wa.ldP[i] = ldP[i]; wa.ldT[i] = ldT[i];
    }
    wcvt_kernel<<<dim3(8, 8, 10), blk, 0, stream>>>(wa);

    csr2_kernel<<<2, 1024, 0, stream>>>(senders, receivers, sst, seid, rst, reid);
    init_out_kernel<<<ALL_ROWS / 256, blk, 0, stream>>>(state, out);

    // ================= FORWARD =================
    enc_h1_kernel<<<ALL_ROWS * 128 / 256, blk, 0, stream>>>(state, enc_e_W1, enc_e_b1,
                                                            enc_n_W1, enc_n_b1, h1eb, menc);
    bgemm<128,2,2,512,512,512, false,false,true,false,false, true,false,false,false,true>
        <<<gA, blk, 0, stream>>>(h1eb, WT0, WT1, eh, up, cup, enc_e_b2, enc_n_b2, cup, ip, ip, mp, up, fp, fp, f2p);
    ln_fwd_kernel<<<ALL_ROWS, blk, 0, stream>>>(eh, eh0b, ehb, rstd);

    for (int k = 0; k < 5; ++k) {
        // G12b = [nh@W1b | nh@W1c] bf16, N=1024
        bgemm<64,4,1,512,512,1024, false,false,false,false,false, false,true,false,false,false>
            <<<gN1024, blk, 0, stream>>>(nhb, WT34, cup, f2p, G12b, cup, fp, fp, cup, ip, ip, mp, up, fp, fp, f2p);
        // fused edge MLP: h1e=relu(eh@W1a+G12[s|r]+b1) [mask]; ehb += h1e@W2+b2
        mlp2<0><<<gF, blk512, 0, stream>>>(ehb, WT2, WT5, pe_b1, pe_b2, G12b,
                                           senders, receivers, mpe + (size_t)k * EL, up, ehb, fp);
        seg_agg_fwd_kernel<<<N_ROWS, blk, 0, stream>>>(ehb, rst, reid, nhb, nsr);
        bgemm<64,4,1,1024,1024,512, false,false,true,true,false, false,true,false,false,false>
            <<<gN512, blk, 0, stream>>>(nsr, WT67, cup, f2p, h1nb, cup, pn_b1, fp, cup, ip, ip, mpn + (size_t)k * NL, up, fp, fp, f2p);
        bgemm<64,4,1,512,512,512, true,false,true,false,false, false,true,false,false,false>
            <<<gN512, blk, 0, stream>>>(h1nb, WT8, cup, f2p, nhb, nhb, pn_b2, fp, cup, ip, ip, mp, up, fp, fp, f2p);
    }

    // fused decoder + decoder-backward: d_eh = ((eh@W1+b1>0)?W2:0) @ W1^T
    mlp2<2><<<gF, blk512, 0, stream>>>(ehb, WT9, WP9, de_b1, fp, cup, ip, ip, mp, up, ehb, de_W2);

    // ================= BACKWARD =================
    for (int k = 4; k >= 0; --k) {
        if (k < 4) {
            bgemm<64,4,1,512,512,512, false,false,false,false,true, false,true,false,false,false>
                <<<gN512, blk, 0, stream>>>(nhb, WP8, cup, f2p, h1nb, cup, fp, fp, cup, ip, ip, mpn + (size_t)k * NL, up, fp, fp, f2p);
            bgemm<64,4,1,512,512,512, true,false,false,false,false, false,true,true,false,false>
                <<<gN1024, blk, 0, stream>>>(h1nb, WP67, cup, f2p, nhb, nhb, fp, fp, cup, ip, ip, mp, G1b, fp, fp, f2p);
            gather_add_kernel<<<E_ROWS * 64 / 256, blk, 0, stream>>>(ehb, G1b, receivers);
        }
        // fused edge MLP bwd: dh1e=(d_eh@We2^T)*mask -> h1eb; ehb += dh1e@We1a^T
        mlp2<1><<<gF, blk512, 0, stream>>>(ehb, WP5, WP2, fp, fp, cup, ip, ip,
                                           mpe + (size_t)k * EL, h1eb, ehb, fp);
        seg_sr_bwd_kernel<<<N_ROWS, blk, 0, stream>>>(h1eb, sst, seid, rst, reid, nsr);
        if (k == 4)
            bgemm<64,4,1,1024,1024,512, false,false,false,false,false, false,true,false,false,false>
                <<<gN512, blk, 0, stream>>>(nsr, WP34c, cup, f2p, nhb, cup, fp, fp, cup, ip, ip, mp, up, fp, fp, f2p);
        else
            bgemm<64,4,1,1024,1024,512, true,false,false,false,false, false,true,false,false,false>
                <<<gN512, blk, 0, stream>>>(nsr, WP34c, cup, f2p, nhb, nhb, fp, fp, cup, ip, ip, mp, up, fp, fp, f2p);
    }

    // encoder backward + fused integrator
    ln_bwd_kernel<<<ALL_ROWS, blk, 0, stream>>>(ehb, eh0b, rstd);
    bgemm<128,2,2,512,512,512, false,false,false,false,true, false,false,false,true,true>
        <<<gA, blk, 0, stream>>>(ehb, WP0, WP1, f2p, up, cup, fp, fp, cup, ip, ip, menc, up, enc_e_W1, enc_n_W1, out);
}

// Round 9
// 1237.322 us; speedup vs baseline: 1.0632x; 1.0632x over previous
//
#include <hip/hip_runtime.h>

// Hamiltonian GNN fwd+grad, out = state - DT*dH.
// Round 9: r7 structure (best known) + T4 counted-vmcnt 3-deep pipelined
// K-loop in bgemm (triple-buffer staging, vmcnt(PER) not 0 in-loop).

#define E_ROWS 16384
#define N_ROWS 4096
#define ALL_ROWS 20480
#define DT_F   0.01f

typedef unsigned char u8;
typedef unsigned short u16;
typedef unsigned long long u64;
typedef __attribute__((ext_vector_type(8))) short short8v;
typedef __attribute__((ext_vector_type(4))) float f32x4;

__device__ __forceinline__ u16 f2b(float f) {
    union { float f; unsigned u; } v; v.f = f;
    unsigned r = v.u + 0x7FFF + ((v.u >> 16) & 1);
    return (u16)(r >> 16);
}
__device__ __forceinline__ float b2f(u16 u) {
    union { unsigned u; float f; } v; v.u = ((unsigned)u) << 16;
    return v.f;
}
__device__ __forceinline__ void gld16(const u16* g, u16* l) {
    __builtin_amdgcn_global_load_lds((const __attribute__((address_space(1))) void*)g,
                                     (__attribute__((address_space(3))) void*)l, 16, 0, 0);
}
template<int N> __device__ __forceinline__ void waitcnt_vm() {
    if constexpr (N == 0)      asm volatile("s_waitcnt vmcnt(0)" ::: "memory");
    else if constexpr (N == 2) asm volatile("s_waitcnt vmcnt(2)" ::: "memory");
    else if constexpr (N == 4) asm volatile("s_waitcnt vmcnt(4)" ::: "memory");
    else if constexpr (N == 8) asm volatile("s_waitcnt vmcnt(8)" ::: "memory");
}

// ---------------------------------------------------------------------------
// bf16 MFMA GEMM, tile BM x (WN*64), 4 waves (WM x WN). Per-wave (BM/WM) x 64.
// LDS: 16-row x 32-k chunks of 512 u16 (linear global_load_lds dest,
// conflict-free ds_read_b128), TRIPLE-buffered. Pipeline (T3+T4): iter t
// issues stage(t+2); computes buf(t); waits vmcnt(PER) (stage(t+1) done,
// stage(t+2) still in flight) -> each load gets ~2 MFMA phases to land.
// Epilogue: acc -> swizzled bf16 LDS tile (aliases staging) -> vectorized
// coalesced readout (short8v / u64 masks). WF32 path: direct f32 stores.
// ---------------------------------------------------------------------------
template<int BM, int WM, int WN, int KTOT, int LDA, int LDC,
         bool ADD_C, bool GATHER2, bool BIAS, bool RELU_MASK, bool APPLY_MASK,
         bool WF32, bool WBF16, bool DUALOUT, bool ROWDOT, bool DECW2, bool BSEL>
__global__ __launch_bounds__(256)
void bgemm(const u16* __restrict__ A, const u16* __restrict__ Bt, const u16* __restrict__ Bt2,
           float* __restrict__ C, u16* __restrict__ Cb,
           const u16* __restrict__ Cinb, const float* __restrict__ bias,
           const float* __restrict__ bias2, const u16* __restrict__ G12b,
           const int* __restrict__ sidx, const int* __restrict__ ridx,
           u8* __restrict__ maskw, u16* __restrict__ C2b,
           const float* __restrict__ wvec, const float* __restrict__ wvec2,
           float* __restrict__ outp)
{
    constexpr int BN = WN * 64;
    constexpr int NA = BM / 16;
    constexpr int TC = (BM + BN) / 16;
    constexpr int PER = TC / 4;
    constexpr int NT = KTOT / 32;
    constexpr int IFRAG = BM / WM / 16;
    constexpr int BUFU = TC * 512;
    constexpr int LSZ = (3 * BUFU > BM * BN) ? 3 * BUFU : BM * BN;
    __shared__ u16 Ls[LSZ];

    const int tid = threadIdx.x;
    const int lane = tid & 63;
    const int wv = tid >> 6;
    const int wr = wv / WN;
    const int wc = wv % WN;

    // XCD-chunked bijective swizzle (grid % 8 == 0 for all grids used)
    const int gx = gridDim.x;
    int id = blockIdx.y * gx + blockIdx.x;
    const int nwg = gx * gridDim.y;
    id = (id & 7) * (nwg >> 3) + (id >> 3);
    const int bx = id % gx;
    const int by = id / gx;
    const int rowBase = by * BM;
    const int colBase = bx * BN;

    const u16* BtU = Bt;
    const float* biasU = bias;
    const float* wvecU = wvec;
    if (BSEL && rowBase >= E_ROWS) { BtU = Bt2; biasU = bias2; wvecU = wvec2; }

    const int srow = lane & 15;
    const int slotk = (lane >> 4) << 3;

    const u16* srcs[PER];
    int dstoff[PER];
#pragma unroll
    for (int q = 0; q < PER; ++q) {
        const int c = wv + (q << 2);
        if (c < NA)
            srcs[q] = A + (size_t)(rowBase + c * 16 + srow) * LDA + slotk;
        else
            srcs[q] = BtU + (size_t)(colBase + (c - NA) * 16 + srow) * KTOT + slotk;
        dstoff[q] = c * 512;
    }

    f32x4 acc[IFRAG][4];
#pragma unroll
    for (int i = 0; i < IFRAG; ++i)
#pragma unroll
        for (int j = 0; j < 4; ++j)
            acc[i][j] = (f32x4){0.f, 0.f, 0.f, 0.f};

    const int fro = ((lane >> 4) << 7) + ((lane & 15) << 3);

    // prologue: stage K-tiles 0 and 1
#pragma unroll
    for (int q = 0; q < PER; ++q) gld16(srcs[q], &Ls[dstoff[q]]);
#pragma unroll
    for (int q = 0; q < PER; ++q) gld16(srcs[q] + 32, &Ls[BUFU + dstoff[q]]);
    waitcnt_vm<PER>();
    __builtin_amdgcn_s_barrier();
    asm volatile("" ::: "memory");

    for (int t = 0; t < NT; ++t) {
        const int cur = t % 3;
        if (t + 2 < NT) {
            const int nxt = (t + 2) % 3;
#pragma unroll
            for (int q = 0; q < PER; ++q)
                gld16(srcs[q] + (t + 2) * 32, &Ls[nxt * BUFU + dstoff[q]]);
        }
        const u16* Lc = &Ls[cur * BUFU];
        short8v af[IFRAG], bfm[4];
#pragma unroll
        for (int i = 0; i < IFRAG; ++i)
            af[i] = *(const short8v*)&Lc[((wr * IFRAG + i) << 9) + fro];
#pragma unroll
        for (int j = 0; j < 4; ++j)
            bfm[j] = *(const short8v*)&Lc[((NA + (wc << 2) + j) << 9) + fro];
#pragma unroll
        for (int i = 0; i < IFRAG; ++i)
#pragma unroll
            for (int j = 0; j < 4; ++j)
                acc[i][j] = __builtin_amdgcn_mfma_f32_16x16x32_bf16(af[i], bfm[j], acc[i][j], 0, 0, 0);
        if (t + 1 < NT) {
            if (t + 2 < NT) waitcnt_vm<PER>();
            else            waitcnt_vm<0>();
            __builtin_amdgcn_s_barrier();
            asm volatile("" ::: "memory");
        }
    }
    __syncthreads();

    if constexpr (WF32) {
        const int colB = colBase + wc * 64 + (lane & 15);
        const int rowB = rowBase + wr * (BM / WM) + ((lane >> 4) << 2);
        float bcol[4];
#pragma unroll
        for (int j = 0; j < 4; ++j) bcol[j] = biasU[colB + (j << 4)];
#pragma unroll
        for (int i = 0; i < IFRAG; ++i)
#pragma unroll
            for (int r = 0; r < 4; ++r) {
                const int row = rowB + (i << 4) + r;
#pragma unroll
                for (int j = 0; j < 4; ++j)
                    C[(size_t)row * LDC + colB + (j << 4)] = acc[i][j][r] + bcol[j];
            }
    } else {
        const int colL = wc * 64 + (lane & 15);
        const int rowL0 = wr * (BM / WM) + ((lane >> 4) << 2);
#pragma unroll
        for (int i = 0; i < IFRAG; ++i)
#pragma unroll
            for (int r = 0; r < 4; ++r) {
                const int row = rowL0 + (i << 4) + r;
#pragma unroll
                for (int j = 0; j < 4; ++j) {
                    const int col = colL + (j << 4);
                    int byte = row * (BN * 2) + col * 2;
                    byte ^= (row & 7) << 4;
                    *(u16*)((char*)Ls + byte) = f2b(acc[i][j][r]);
                }
            }
        __syncthreads();

        constexpr int TPR = BN / 8;
        constexpr int RPP = 256 / TPR;
        constexpr int NP = BM / RPP;
        const int rloc = tid / TPR;
        const int seg = tid % TPR;
        const int col0 = seg * 8;
        const bool upper = DUALOUT && (colBase >= 512);
#pragma unroll
        for (int p = 0; p < NP; ++p) {
            const int row = p * RPP + rloc;
            const int grow = rowBase + row;
            const int gcol = colBase + col0;
            int byte = row * (BN * 2) + col0 * 2;
            byte ^= (row & 7) << 4;
            const short8v sv = *(const short8v*)((const char*)Ls + byte);
            float v[8];
#pragma unroll
            for (int e = 0; e < 8; ++e) v[e] = b2f((u16)sv[e]);

            if (DUALOUT && upper) {
                short8v res;
#pragma unroll
                for (int e = 0; e < 8; ++e) res[e] = (short)f2b(v[e]);
                *(short8v*)&C2b[(size_t)grow * 512 + (gcol - 512)] = res;
                continue;
            }
            if (GATHER2) {
                const int si = sidx[grow], ri = ridx[grow];
                const short8v g1 = *(const short8v*)&G12b[(size_t)si * 1024 + gcol];
                const short8v g2 = *(const short8v*)&G12b[(size_t)ri * 1024 + 512 + gcol];
#pragma unroll
                for (int e = 0; e < 8; ++e) v[e] += b2f((u16)g1[e]) + b2f((u16)g2[e]);
            }
            if (ADD_C) {
                const short8v c8 = *(const short8v*)&Cinb[(size_t)grow * LDC + gcol];
#pragma unroll
                for (int e = 0; e < 8; ++e) v[e] += b2f((u16)c8[e]);
            }
            if (BIAS) {
                const float4 b0 = *(const float4*)&biasU[gcol];
                const float4 b1 = *(const float4*)&biasU[gcol + 4];
                v[0] += b0.x; v[1] += b0.y; v[2] += b0.z; v[3] += b0.w;
                v[4] += b1.x; v[5] += b1.y; v[6] += b1.z; v[7] += b1.w;
            }
            if (DECW2) {
                const float4 w0 = *(const float4*)&wvecU[gcol];
                const float4 w1 = *(const float4*)&wvecU[gcol + 4];
                const float wl[8] = {w0.x, w0.y, w0.z, w0.w, w1.x, w1.y, w1.z, w1.w};
                short8v res;
#pragma unroll
                for (int e = 0; e < 8; ++e) res[e] = (v[e] > 0.f) ? (short)f2b(wl[e]) : (short)0;
                *(short8v*)&Cb[(size_t)grow * LDC + gcol] = res;
                continue;
            }
            if (RELU_MASK) {
                u64 mm = 0;
#pragma unroll
                for (int e = 0; e < 8; ++e) {
                    const bool m = v[e] > 0.f;
                    mm |= (u64)(m ? 1 : 0) << (e * 8);
                    if (!m) v[e] = 0.f;
                }
                *(u64*)&maskw[(size_t)grow * 512 + gcol] = mm;
            }
            if (APPLY_MASK) {
                const u64 mm = *(const u64*)&maskw[(size_t)grow * 512 + gcol];
#pragma unroll
                for (int e = 0; e < 8; ++e)
                    if (!((mm >> (e * 8)) & 0xff)) v[e] = 0.f;
            }
            if (ROWDOT) {
                const float4 w0 = *(const float4*)&wvecU[gcol];
                const float4 w1 = *(const float4*)&wvecU[gcol + 4];
                float rds = v[0] * w0.x + v[1] * w0.y + v[2] * w0.z + v[3] * w0.w
                          + v[4] * w1.x + v[5] * w1.y + v[6] * w1.z + v[7] * w1.w;
#pragma unroll
                for (int m = 1; m < TPR; m <<= 1) rds += __shfl_xor(rds, m);
                if (seg == 0) atomicAdd(outp + grow, -DT_F * rds);
            }
            if (WBF16) {
                short8v res;
#pragma unroll
                for (int e = 0; e < 8; ++e) res[e] = (short)f2b(v[e]);
                *(short8v*)&Cb[(size_t)grow * LDC + gcol] = res;
            }
        }
    }
}

// ---------------------------------------------------------------------------
struct WArgs {
    const float* src[10];
    u16* dstP[10];
    u16* dstT[10];
    int ldP[10], ldT[10];
};

__global__ void wcvt_kernel(WArgs a)
{
    const int i = blockIdx.z;
    const float* W = a.src[i];
    u16* P = a.dstP[i]; const int lp = a.ldP[i];
    u16* T = a.dstT[i]; const int lt = a.ldT[i];
    __shared__ u16 t[64][66];
    const int rb = blockIdx.y << 6, cb = blockIdx.x << 6;
    const int tr = threadIdx.x >> 4;
    const int tc = (threadIdx.x & 15) << 2;
#pragma unroll
    for (int rr = 0; rr < 4; ++rr) {
        const int r = tr + (rr << 4);
        const float4 v = *(const float4*)&W[(size_t)(rb + r) * 512 + cb + tc];
        ushort4 u; u.x = f2b(v.x); u.y = f2b(v.y); u.z = f2b(v.z); u.w = f2b(v.w);
        *(ushort4*)&P[(size_t)(rb + r) * lp + cb + tc] = u;
        t[r][tc] = u.x; t[r][tc + 1] = u.y; t[r][tc + 2] = u.z; t[r][tc + 3] = u.w;
    }
    __syncthreads();
#pragma unroll
    for (int rr = 0; rr < 4; ++rr) {
        const int n = tr + (rr << 4);
        ushort4 u;
        u.x = t[tc][n]; u.y = t[tc + 1][n]; u.z = t[tc + 2][n]; u.w = t[tc + 3][n];
        *(ushort4*)&T[(size_t)(cb + n) * lt + rb + tc] = u;
    }
}

// ---------------------------------------------------------------------------
__device__ void csr_build(const int* __restrict__ idx, int* __restrict__ starts,
                          int* __restrict__ eids)
{
    __shared__ int hist[4096];
    __shared__ int scanbuf[1024];
    const int t = threadIdx.x;
    for (int i = t; i < 4096; i += 1024) hist[i] = 0;
    __syncthreads();
    for (int e = t; e < 16384; e += 1024) atomicAdd(&hist[idx[e]], 1);
    __syncthreads();
    const int base = t << 2;
    const int l0 = hist[base], l1 = hist[base + 1], l2 = hist[base + 2], l3 = hist[base + 3];
    const int lsum = l0 + l1 + l2 + l3;
    scanbuf[t] = lsum;
    __syncthreads();
    for (int ofs = 1; ofs < 1024; ofs <<= 1) {
        const int v = scanbuf[t];
        const int u = (t >= ofs) ? scanbuf[t - ofs] : 0;
        __syncthreads();
        scanbuf[t] = v + u;
        __syncthreads();
    }
    const int excl = scanbuf[t] - lsum;
    const int p0 = excl, p1 = p0 + l0, p2 = p1 + l1, p3 = p2 + l2;
    starts[base] = p0; starts[base + 1] = p1; starts[base + 2] = p2; starts[base + 3] = p3;
    if (t == 0) starts[4096] = 16384;
    __syncthreads();
    hist[base] = p0; hist[base + 1] = p1; hist[base + 2] = p2; hist[base + 3] = p3;
    __syncthreads();
    for (int e = t; e < 16384; e += 1024) {
        const int pos = atomicAdd(&hist[idx[e]], 1);
        eids[pos] = e;
    }
    __syncthreads();
    for (int n = t; n < 4096; n += 1024) {
        const int s0 = starts[n], s1 = hist[n];
        for (int i = s0 + 1; i < s1; ++i) {
            const int v = eids[i];
            int j = i - 1;
            while (j >= s0 && eids[j] > v) { eids[j + 1] = eids[j]; --j; }
            eids[j + 1] = v;
        }
    }
}

__global__ __launch_bounds__(1024) void csr2_kernel(const int* __restrict__ senders,
                                                    const int* __restrict__ receivers,
                                                    int* __restrict__ sst, int* __restrict__ seid,
                                                    int* __restrict__ rst, int* __restrict__ reid)
{
    if (blockIdx.x == 0) csr_build(receivers, rst, reid);
    else                 csr_build(senders, sst, seid);
}

__global__ void init_out_kernel(const float* __restrict__ state, float* __restrict__ out)
{
    const int t = blockIdx.x * 256 + threadIdx.x;
    out[t] = state[t];
}

__global__ void seg_agg_fwd_kernel(const u16* __restrict__ ehb, const int* __restrict__ starts,
                                   const int* __restrict__ eids, const u16* __restrict__ nhb,
                                   u16* __restrict__ nagg)
{
    const int n = blockIdx.x, c = threadIdx.x;
    const int s0 = starts[n], s1 = starts[n + 1];
    float a0 = 0.f, a1 = 0.f;
    for (int i = s0; i < s1; ++i) {
        const u16* p = ehb + (size_t)eids[i] * 512;
        a0 += b2f(p[c]); a1 += b2f(p[c + 256]);
    }
    u16* d = nagg + (size_t)n * 1024;
    const u16* s = nhb + (size_t)n * 512;
    d[c] = s[c]; d[c + 256] = s[c + 256];
    d[512 + c] = f2b(a0); d[768 + c] = f2b(a1);
}

__global__ void seg_sr_bwd_kernel(const u16* __restrict__ dh1e,
                                  const int* __restrict__ sst, const int* __restrict__ seid,
                                  const int* __restrict__ rst, const int* __restrict__ reid,
                                  u16* __restrict__ SR)
{
    const int n = blockIdx.x, c = threadIdx.x;
    float a0 = 0.f, a1 = 0.f, b0 = 0.f, b1 = 0.f;
    for (int i = sst[n]; i < sst[n + 1]; ++i) {
        const u16* p = dh1e + (size_t)seid[i] * 512;
        a0 += b2f(p[c]); a1 += b2f(p[c + 256]);
    }
    for (int i = rst[n]; i < rst[n + 1]; ++i) {
        const u16* p = dh1e + (size_t)reid[i] * 512;
        b0 += b2f(p[c]); b1 += b2f(p[c + 256]);
    }
    u16* d = SR + (size_t)n * 1024;
    d[c] = f2b(a0); d[c + 256] = f2b(a1);
    d[512 + c] = f2b(b0); d[768 + c] = f2b(b1);
}

__global__ void enc_h1_kernel(const float* __restrict__ x,
                              const float* __restrict__ W1e, const float* __restrict__ b1e,
                              const float* __restrict__ W1n, const float* __restrict__ b1n,
                              u16* __restrict__ h1b, u8* __restrict__ mask)
{
    const int idx = blockIdx.x * 256 + threadIdx.x;
    const int row = idx >> 7;
    const int c = (idx & 127) << 2;
    const bool edge = row < E_ROWS;
    const float* W1 = edge ? W1e : W1n;
    const float* b1 = edge ? b1e : b1n;
    const float xv = x[row];
    const float4 w = *(const float4*)&W1[c];
    const float4 b = *(const float4*)&b1[c];
    float4 v;
    v.x = fmaf(xv, w.x, b.x); v.y = fmaf(xv, w.y, b.y);
    v.z = fmaf(xv, w.z, b.z); v.w = fmaf(xv, w.w, b.w);
    uchar4 m;
    m.x = v.x > 0.f; m.y = v.y > 0.f; m.z = v.z > 0.f; m.w = v.w > 0.f;
    v.x = m.x ? v.x : 0.f; v.y = m.y ? v.y : 0.f;
    v.z = m.z ? v.z : 0.f; v.w = m.w ? v.w : 0.f;
    const size_t o = (size_t)row * 512 + c;
    ushort4 u; u.x = f2b(v.x); u.y = f2b(v.y); u.z = f2b(v.z); u.w = f2b(v.w);
    *(ushort4*)&h1b[o] = u;
    *(uchar4*)&mask[o] = m;
}

__global__ void ln_fwd_kernel(const float* __restrict__ x, u16* __restrict__ xhat_b,
                              u16* __restrict__ xb, float* __restrict__ rstd_save)
{
    const int row = blockIdx.x, tid = threadIdx.x;
    const float* p = x + (size_t)row * 512;
    const float a = p[tid], b = p[tid + 256];
    __shared__ float s1[256], s2[256];
    s1[tid] = a + b; s2[tid] = a * a + b * b;
    __syncthreads();
    for (int d = 128; d > 0; d >>= 1) {
        if (tid < d) { s1[tid] += s1[tid + d]; s2[tid] += s2[tid + d]; }
        __syncthreads();
    }
    const float mean = s1[0] * (1.f / 512.f);
    const float var = s2[0] * (1.f / 512.f) - mean * mean;
    const float r = rsqrtf(var + 1e-6f);
    const float ya = (a - mean) * r, yb = (b - mean) * r;
    const size_t o = (size_t)row * 512 + tid;
    xhat_b[o] = f2b(ya); xhat_b[o + 256] = f2b(yb);
    xb[o] = f2b(ya); xb[o + 256] = f2b(yb);
    if (tid == 0) rstd_save[row] = r;
}

__global__ void ln_bwd_kernel(u16* __restrict__ d, const u16* __restrict__ xhat_b,
                              const float* __restrict__ rstd)
{
    const int row = blockIdx.x, tid = threadIdx.x;
    u16* p = d + (size_t)row * 512;
    const u16* xh = xhat_b + (size_t)row * 512;
    const float da = b2f(p[tid]), dbv = b2f(p[tid + 256]);
    const float xa = b2f(xh[tid]), xbv = b2f(xh[tid + 256]);
    __shared__ float s1[256], s2[256];
    s1[tid] = da + dbv; s2[tid] = da * xa + dbv * xbv;
    __syncthreads();
    for (int dd = 128; dd > 0; dd >>= 1) {
        if (tid < dd) { s1[tid] += s1[tid + dd]; s2[tid] += s2[tid + dd]; }
        __syncthreads();
    }
    const float m1 = s1[0] * (1.f / 512.f);
    const float m2 = s2[0] * (1.f / 512.f);
    const float r = rstd[row];
    p[tid] = f2b(r * (da - m1 - xa * m2));
    p[tid + 256] = f2b(r * (dbv - m1 - xbv * m2));
}

__global__ void gather_add_kernel(u16* __restrict__ dst, const u16* __restrict__ src,
                                  const int* __restrict__ idx)
{
    const int t = blockIdx.x * 256 + threadIdx.x;
    const int row = t >> 6;
    const int c = (t & 63) << 3;
    const size_t o = (size_t)row * 512 + c;
    short8v a = *(const short8v*)&dst[o];
    const short8v g = *(const short8v*)&src[(size_t)idx[row] * 512 + c];
    short8v r;
#pragma unroll
    for (int i = 0; i < 8; ++i)
        r[i] = (short)f2b(b2f((u16)a[i]) + b2f((u16)g[i]));
    *(short8v*)&dst[o] = r;
}

// ---------------------------------------------------------------------------
extern "C" void kernel_launch(void* const* d_in, const int* in_sizes, int n_in,
                              void* d_out, int out_size, void* d_ws, size_t ws_size,
                              hipStream_t stream)
{
    (void)in_sizes; (void)n_in; (void)out_size; (void)ws_size;
    const float* state     = (const float*)d_in[0];
    const int*   senders   = (const int*)d_in[1];
    const int*   receivers = (const int*)d_in[2];
    const float* enc_e_W1 = (const float*)d_in[3];
    const float* enc_e_b1 = (const float*)d_in[4];
    const float* enc_e_W2 = (const float*)d_in[5];
    const float* enc_e_b2 = (const float*)d_in[6];
    const float* enc_n_W1 = (const float*)d_in[7];
    const float* enc_n_b1 = (const float*)d_in[8];
    const float* enc_n_W2 = (const float*)d_in[9];
    const float* enc_n_b2 = (const float*)d_in[10];
    const float* pe_W1 = (const float*)d_in[11];
    const float* pe_b1 = (const float*)d_in[12];
    const float* pe_W2 = (const float*)d_in[13];
    const float* pe_b2 = (const float*)d_in[14];
    const float* pn_W1 = (const float*)d_in[15];
    const float* pn_b1 = (const float*)d_in[16];
    const float* pn_W2 = (const float*)d_in[17];
    const float* pn_b2 = (const float*)d_in[18];
    const float* de_W1 = (const float*)d_in[19];
    const float* de_b1 = (const float*)d_in[20];
    const float* de_W2 = (const float*)d_in[21];
    float* out = (float*)d_out;

    const size_t EL = (size_t)E_ROWS * 512, NL = (size_t)N_ROWS * 512;
    const size_t AL = (size_t)ALL_ROWS * 512;
    const size_t LL = 512 * 512;
    char* w = (char*)d_ws;
    size_t off = 0;
    auto carve = [&](size_t bytes) -> char* {
        char* p = w + off;
        off += (bytes + 255) & ~(size_t)255;
        return p;
    };
    u16* wb = (u16*)carve(20 * LL * 2);
    u16* WT0 = wb;           u16* WT1 = wb + LL;      u16* WT2 = wb + 2 * LL;
    u16* WT34 = wb + 3 * LL;                          u16* WT5 = wb + 5 * LL;
    u16* WT8 = wb + 6 * LL;  u16* WT9 = wb + 7 * LL;
    u16* WP0 = wb + 8 * LL;  u16* WP1 = wb + 9 * LL;  u16* WP2 = wb + 10 * LL;
    u16* WP5 = wb + 11 * LL; u16* WP8 = wb + 12 * LL; u16* WP9 = wb + 13 * LL;
    u16* WT67 = wb + 14 * LL;   // [512][1024]
    u16* WP34c = wb + 16 * LL;  // [512][1024]
    u16* WP67 = wb + 18 * LL;   // [1024][512]

    float* eh  = (float*)carve(AL * 4);
    u16* ehb   = (u16*)carve(EL * 2);
    u16* nhb   = (u16*)carve(NL * 2);
    u16* h1eb  = (u16*)carve(EL * 2);
    u16* h1nb  = (u16*)carve(NL * 2);
    u16* eh0b  = (u16*)carve(EL * 2);
    u16* nh0b  = (u16*)carve(NL * 2);
    u8* menc   = (u8*)carve(AL);
    u16* G1b   = (u16*)carve(NL * 2);
    u16* G12b  = (u16*)carve(NL * 2 * 2);
    u16* nsr   = (u16*)carve(NL * 2 * 2);
    float* rstd = (float*)carve(ALL_ROWS * 4);
    u8* mpe    = (u8*)carve(5 * EL);
    u8* mpn    = (u8*)carve(5 * NL);
    int* rst  = (int*)carve(4097 * 4);
    int* reid = (int*)carve(16384 * 4);
    int* sst  = (int*)carve(4097 * 4);
    int* seid = (int*)carve(16384 * 4);

    const dim3 blk(256);
    const dim3 gE(4, E_ROWS / 128);           // edge GEMMs: 512 blocks
    const dim3 gA(4, ALL_ROWS / 128);         // merged enc/final: 640 blocks
    const dim3 gN512(8, N_ROWS / 64);         // node N=512: 512 blocks
    const dim3 gN1024(16, N_ROWS / 64);       // node N=1024: 1024 blocks
    const float* fp = nullptr;
    u16* up = nullptr;
    const u16* cup = nullptr;
    const int* ip = nullptr;
    u8* mp = nullptr;
    float* f2p = nullptr;

    WArgs wa;
    const float* wsrc[10] = { enc_e_W2, enc_n_W2, pe_W1, pe_W1 + LL, pe_W1 + 2 * LL,
                              pe_W2, pn_W1, pn_W1 + LL, pn_W2, de_W1 };
    u16* dstP[10] = { WP0, WP1, WP2, WP34c, WP34c + 512, WP5, WP67, WP67 + LL, WP8, WP9 };
    int  ldP [10] = { 512, 512, 512, 1024,  1024,        512, 512,  512,       512, 512 };
    u16* dstT[10] = { WT0, WT1, WT2, WT34, WT34 + LL, WT5, WT67, WT67 + 512, WT8, WT9 };
    int  ldT [10] = { 512, 512, 512, 512,  512,       512, 1024, 1024,       512, 512 };
    for (int i = 0; i < 10; ++i) {
        wa.src[i] = wsrc[i]; wa.dstP[i] = dstP[i]; wa.dstT[i] = dstT[i];
        wa.ldP[i] = ldP[i]; wa.ldT[i] = ldT[i];
    }
    wcvt_kernel<<<dim3(8, 8, 10), blk, 0, stream>>>(wa);

    csr2_kernel<<<2, 1024, 0, stream>>>(senders, receivers, sst, seid, rst, reid);
    init_out_kernel<<<ALL_ROWS / 256, blk, 0, stream>>>(state, out);

    // ================= FORWARD =================
    enc_h1_kernel<<<ALL_ROWS * 128 / 256, blk, 0, stream>>>(state, enc_e_W1, enc_e_b1,
                                                            enc_n_W1, enc_n_b1, h1eb, menc);
    bgemm<128,2,2,512,512,512, false,false,true,false,false, true,false,false,false,false,true>
        <<<gA, blk, 0, stream>>>(h1eb, WT0, WT1, eh, up, cup, enc_e_b2, enc_n_b2, cup, ip, ip, mp, up, fp, fp, f2p);
    ln_fwd_kernel<<<ALL_ROWS, blk, 0, stream>>>(eh, eh0b, ehb, rstd);

    for (int k = 0; k < 5; ++k) {
        bgemm<64,4,1,512,512,1024, false,false,false,false,false, false,true,false,false,false,false>
            <<<gN1024, blk, 0, stream>>>(nhb, WT34, cup, f2p, G12b, cup, fp, fp, cup, ip, ip, mp, up, fp, fp, f2p);
        bgemm<128,2,2,512,512,512, false,true,true,true,false, false,true,false,false,false,false>
            <<<gE, blk, 0, stream>>>(ehb, WT2, cup, f2p, h1eb, cup, pe_b1, fp, G12b, senders, receivers, mpe + (size_t)k * EL, up, fp, fp, f2p);
        bgemm<128,2,2,512,512,512, true,false,true,false,false, false,true,false,false,false,false>
            <<<gE, blk, 0, stream>>>(h1eb, WT5, cup, f2p, ehb, ehb, pe_b2, fp, cup, ip, ip, mp, up, fp, fp, f2p);
        seg_agg_fwd_kernel<<<N_ROWS, blk, 0, stream>>>(ehb, rst, reid, nhb, nsr);
        bgemm<64,4,1,1024,1024,512, false,false,true,true,false, false,true,false,false,false,false>
            <<<gN512, blk, 0, stream>>>(nsr, WT67, cup, f2p, h1nb, cup, pn_b1, fp, cup, ip, ip, mpn + (size_t)k * NL, up, fp, fp, f2p);
        bgemm<64,4,1,512,512,512, true,false,true,false,false, false,true,false,false,false,false>
            <<<gN512, blk, 0, stream>>>(h1nb, WT8, cup, f2p, nhb, nhb, pn_b2, fp, cup, ip, ip, mp, up, fp, fp, f2p);
    }

    bgemm<128,2,2,512,512,512, false,false,true,false,false, false,false,false,false,true,false>
        <<<gE, blk, 0, stream>>>(ehb, WT9, cup, f2p, h1eb, cup, de_b1, fp, cup, ip, ip, mp, up, de_W2, fp, f2p);

    // ================= BACKWARD =================
    bgemm<128,2,2,512,512,512, false,false,false,false,false, false,true,false,false,false,false>
        <<<gE, blk, 0, stream>>>(h1eb, WP9, cup, f2p, ehb, cup, fp, fp, cup, ip, ip, mp, up, fp, fp, f2p);

    for (int k = 4; k >= 0; --k) {
        if (k < 4) {
            bgemm<64,4,1,512,512,512, false,false,false,false,true, false,true,false,false,false,false>
                <<<gN512, blk, 0, stream>>>(nhb, WP8, cup, f2p, h1nb, cup, fp, fp, cup, ip, ip, mpn + (size_t)k * NL, up, fp, fp, f2p);
            bgemm<64,4,1,512,512,512, true,false,false,false,false, false,true,true,false,false,false>
                <<<gN1024, blk, 0, stream>>>(h1nb, WP67, cup, f2p, nhb, nhb, fp, fp, cup, ip, ip, mp, G1b, fp, fp, f2p);
            gather_add_kernel<<<E_ROWS * 64 / 256, blk, 0, stream>>>(ehb, G1b, receivers);
        }
        bgemm<128,2,2,512,512,512, false,false,false,false,true, false,true,false,false,false,false>
            <<<gE, blk, 0, stream>>>(ehb, WP5, cup, f2p, h1eb, cup, fp, fp, cup, ip, ip, mpe + (size_t)k * EL, up, fp, fp, f2p);
        bgemm<128,2,2,512,512,512, true,false,false,false,false, false,true,false,false,false,false>
            <<<gE, blk, 0, stream>>>(h1eb, WP2, cup, f2p, ehb, ehb, fp, fp, cup, ip, ip, mp, up, fp, fp, f2p);
        seg_sr_bwd_kernel<<<N_ROWS, blk, 0, stream>>>(h1eb, sst, seid, rst, reid, nsr);
        if (k == 4)
            bgemm<64,4,1,1024,1024,512, false,false,false,false,false, false,true,false,false,false,false>
                <<<gN512, blk, 0, stream>>>(nsr, WP34c, cup, f2p, nhb, cup, fp, fp, cup, ip, ip, mp, up, fp, fp, f2p);
        else
            bgemm<64,4,1,1024,1024,512, true,false,false,false,false, false,true,false,false,false,false>
                <<<gN512, blk, 0, stream>>>(nsr, WP34c, cup, f2p, nhb, nhb, fp, fp, cup, ip, ip, mp, up, fp, fp, f2p);
    }

    ln_bwd_kernel<<<ALL_ROWS, blk, 0, stream>>>(ehb, eh0b, rstd);
    bgemm<128,2,2,512,512,512, false,false,false,false,true, false,false,false,true,false,true>
        <<<gA, blk, 0, stream>>>(ehb, WP0, WP1, f2p, up, cup, fp, fp, cup, ip, ip, menc, up, enc_e_W1, enc_n_W1, out);
}